// Round 3
// baseline (346.617 us; speedup 1.0000x reference)
//
#include <hip/hip_runtime.h>

#define B 4
#define C 48
#define C3 144
#define H 256
#define W 256
#define HW 65536
#define EPSN 1e-12f

// ---- a1 tiling: 16x12 output tile, 18x14 halo (252 positions) ----
#define TSX 16
#define TSY 12
#define HSX 18
#define HSY 14
#define NTX 16           // 256/16
#define NTY 22           // ceil(256/12)
#define NPIX2 192        // TSX*TSY
#define NHALO 252        // HSX*HSY

#define NCHUNK 128       // gram chunks per batch
#define CHUNK 512        // pixels per gram chunk
#define LP 68            // padded LDS row stride for a2 (float4-aligned, <=2-way banks)

// Round-9 theory: every remaining kernel was LDS-issue-pipe bound (one LDS
// pipe per CU vs 4 SIMDs; >=1 LDS instr per 4 FMA saturates it at <=25%
// VALUBusy). Fixes: a2/s_dw/a4 pixel-vectorized (b128 LDS reads, 6 reads per
// 36 FMA); s_conv1x1 weights moved from the blocking in-order s_load path to
// per-lane VMEM loads (asm-forced divergent base -> global_load_dwordx4,
// 64-same-addr lanes coalesce to one L1 line, vmcnt pipelines).
#define S_QKV_OFF  ((size_t)0)
#define S_DWQ_OFF  (S_QKV_OFF + (size_t)B * C3 * HW)
#define S_DWK_OFF  (S_DWQ_OFF + (size_t)B * C * HW)
#define S_SP_OFF   (S_DWK_OFF + (size_t)B * C * HW)
#define S_NQP_OFF  (S_SP_OFF + (size_t)B * NCHUNK * C * C)
#define S_NKP_OFF  (S_NQP_OFF + (size_t)B * NCHUNK * C)
#define S_S_OFF    (S_NKP_OFF + (size_t)B * NCHUNK * C)
#define S_NQ_OFF   (S_S_OFF + (size_t)B * C * C)
#define S_NK_OFF   (S_NQ_OFF + (size_t)B * C)
#define S_M_OFF    (S_NK_OFF + (size_t)B * C)
#define S_WT_OFF   (S_M_OFF + (size_t)B * C * C)
#define S_FLOATS   (S_WT_OFF + (size_t)C3 * C)

// ================= PATH A workspace layout (floats), ~106 MB =================
#define A_DWQ_OFF  ((size_t)0)
#define A_DWK_OFF  (A_DWQ_OFF + (size_t)B * C * HW)
#define A_SP_OFF   (A_DWK_OFF + (size_t)B * C * HW)            // B*128*2304
#define A_NQP_OFF  (A_SP_OFF + (size_t)B * NCHUNK * C * C)     // B*128*48
#define A_NKP_OFF  (A_NQP_OFF + (size_t)B * NCHUNK * C)
#define A_S_OFF    (A_NKP_OFF + (size_t)B * NCHUNK * C)        // B*2304
#define A_NQ_OFF   (A_S_OFF + (size_t)B * C * C)               // B*48
#define A_NK_OFF   (A_NQ_OFF + (size_t)B * C)
#define A_M_OFF    (A_NK_OFF + (size_t)B * C)                  // B*2304
#define A_FLOATS   (A_M_OFF + (size_t)B * C * C)

// ================= PATH B (fallback) workspace layout, ~75 KB ================
#define B_S_OFF  0
#define B_NQ_OFF (B * C * C)
#define B_NK_OFF (B_NQ_OFF + B * C)
#define B_M_OFF  (B_NK_OFF + B * C)
#define B_ZERO_N (B * C * C + 2 * B * C)

// force a (wave-uniform) value into a VGPR so divergence analysis can't
// scalarize dependent loads back onto the in-order SMEM path
__device__ __forceinline__ int force_vgpr(int v) {
  asm("v_mov_b32 %0, %1" : "=v"(v) : "v"(v));
  return v;
}

// ============================ PATH S kernels =================================

// S0: transpose qkv 1x1 weights [144][48] -> wT [48][144].
__global__ __launch_bounds__(256) void s_wt(
    const float* __restrict__ w1, float* __restrict__ wT) {
  const int i = blockIdx.x * 256 + threadIdx.x;
  if (i < C3 * C) {
    const int oc = i / C, d = i - oc * C;
    wT[d * C3 + oc] = w1[i];
  }
}

// S1: 1x1 conv as GEMM. Block = 256 contiguous pixels, all 144 out-channels
// in 3 oc-group passes over one 48 KB x-tile. Thread owns 4 px (1 b128 LDS
// read per k-step); wave owns 12 oc. Round-9: weights per-lane VMEM
// (global_load_dwordx4, L1-resident 2.3 KB/group) -- the round-8 s_load
// version stalled on in-order lgkmcnt (VALUBusy 34% = exact FMA floor).
__global__ __launch_bounds__(256) void s_conv1x1(
    const float* __restrict__ x, const float* __restrict__ wT,
    float* __restrict__ qkv) {
  __shared__ float xs[C * 256];      // 48 KB
  const int t = threadIdx.x;
  const int bb = blockIdx.x >> 8;                // 256 pixel-tiles per batch
  const int p0 = (blockIdx.x & 255) << 8;        // 256 px per tile
  const float* xb = x + (size_t)bb * C * HW + p0;
#pragma unroll
  for (int j = 0; j < 12; ++j) {                 // 3072 float4 = 48x256
    const int f = t + j * 256;
    const int d = f >> 6, p4 = (f & 63) * 4;
    *(float4*)&xs[d * 256 + p4] = *(const float4*)&xb[(size_t)d * HW + p4];
  }
  __syncthreads();
  const int pl = (t & 63) * 4;                   // this thread's 4 pixels
  const int ocw = force_vgpr((t >> 6) * 12);     // divergent -> VMEM weights
#pragma unroll 1
  for (int g = 0; g < 3; ++g) {
    const int oc0 = g * 48 + ocw;
    const float* wp = wT + oc0;                  // per-lane (same-addr) base
    float acc[12][4];
#pragma unroll
    for (int o = 0; o < 12; ++o)
#pragma unroll
      for (int p = 0; p < 4; ++p) acc[o][p] = 0.f;
#pragma unroll 4
    for (int d = 0; d < C; ++d) {
      const float4 xv = *(const float4*)&xs[d * 256 + pl];
      const float xa[4] = {xv.x, xv.y, xv.z, xv.w};
#pragma unroll
      for (int jj = 0; jj < 3; ++jj) {
        const float4 wv = *(const float4*)&wp[d * C3 + jj * 4];
        const float wa[4] = {wv.x, wv.y, wv.z, wv.w};
#pragma unroll
        for (int o = 0; o < 4; ++o)
#pragma unroll
          for (int p = 0; p < 4; ++p)
            acc[jj * 4 + o][p] = fmaf(wa[o], xa[p], acc[jj * 4 + o][p]);
      }
    }
    float* ob = qkv + ((size_t)bb * C3 + oc0) * HW + p0 + pl;
#pragma unroll
    for (int o = 0; o < 12; ++o) {
      float4 v;
      v.x = acc[o][0]; v.y = acc[o][1]; v.z = acc[o][2]; v.w = acc[o][3];
      *(float4*)&ob[(size_t)o * HW] = v;
    }
  }
}

// S2: depthwise 3x3, streaming. Block = one (batch, channel, 16-row band).
// Round-9: 4 px/thread; window read as b128+b64 (6 LDS reads / 36 FMA vs the
// old 9 b32 / 9 FMA) -> LDS demand drops 3.6x, kernel becomes HBM-bound.
// Layout: rows -1..16 at cols 1..256 of a stride-260 row (col 0,257 = zero
// pads). Window for outputs x..x+3 starts at padded col x (16B-aligned).
#define DWR 16
__global__ __launch_bounds__(256) void s_dw(
    const float* __restrict__ qkv, const float* __restrict__ w9,
    float* __restrict__ dwq, float* __restrict__ dwk,
    float* __restrict__ vout) {
  __shared__ float ls[18 * 260];
  const int t = threadIdx.x;
  const int rblk = blockIdx.x & 15;
  const int cb = blockIdx.x >> 4;                // bb*144 + c
  const int c = cb % C3;
  const int bb = cb / C3;
  const int r0 = rblk * DWR;
  const float* src = qkv + (size_t)cb * HW;
#pragma unroll
  for (int f = t; f < 18 * 256; f += 256) {      // 18 iterations exactly
    const int rr = f >> 8, xc = f & 255;
    const int gr = r0 - 1 + rr;
    ls[rr * 260 + 1 + xc] = (gr >= 0 && gr < H) ? src[gr * W + xc] : 0.f;
  }
  if (t < 18) { ls[t * 260] = 0.f; ls[t * 260 + 257] = 0.f; }
  const float* wp = w9 + c * 9;                  // uniform -> s_load (tiny)
  float wv[9];
#pragma unroll
  for (int k = 0; k < 9; ++k) wv[k] = wp[k];
  __syncthreads();
  float* dst;
  int cc;
  if (c < C)          { dst = dwq;  cc = c; }
  else if (c < 2 * C) { dst = dwk;  cc = c - C; }
  else                { dst = vout; cc = c - 2 * C; }
  float* ob = dst + ((size_t)bb * C + cc) * HW;
  const int xq = (t & 63) * 4;                   // 4 output cols per thread
  const int rw = t >> 6;                         // wave owns every 4th row
#pragma unroll
  for (int rr = rw; rr < DWR; rr += 4) {
    const float* l0 = ls + rr * 260 + xq;        // padded col xq == global x-1
    const float4 a0 = *(const float4*)&l0[0];
    const float2 b0 = *(const float2*)&l0[4];
    const float4 a1 = *(const float4*)&l0[260];
    const float2 b1 = *(const float2*)&l0[264];
    const float4 a2 = *(const float4*)&l0[520];
    const float2 b2 = *(const float2*)&l0[524];
    const float r0e[6] = {a0.x, a0.y, a0.z, a0.w, b0.x, b0.y};
    const float r1e[6] = {a1.x, a1.y, a1.z, a1.w, b1.x, b1.y};
    const float r2e[6] = {a2.x, a2.y, a2.z, a2.w, b2.x, b2.y};
    float4 o;
    float* op = &o.x;
#pragma unroll
    for (int j = 0; j < 4; ++j) {
      float d = wv[0] * r0e[j] + wv[1] * r0e[j + 1] + wv[2] * r0e[j + 2];
      d = fmaf(wv[3], r1e[j], d);
      d = fmaf(wv[4], r1e[j + 1], d);
      d = fmaf(wv[5], r1e[j + 2], d);
      d = fmaf(wv[6], r2e[j], d);
      d = fmaf(wv[7], r2e[j + 1], d);
      d = fmaf(wv[8], r2e[j + 2], d);
      op[j] = d;
    }
    *(float4*)&ob[(r0 + rr) * W + xq] = o;
  }
}

// ============================ PATH A kernels =================================

// A1: 1x1 conv + depthwise 3x3 fused (fallback path only).
__global__ __launch_bounds__(256) void a1_conv_dw(
    const float* __restrict__ x, const float* __restrict__ w1,
    const float* __restrict__ w9, float* __restrict__ dwq,
    float* __restrict__ dwk, float* __restrict__ vout) {
  __shared__ float xs[C * 256];
  __shared__ float qs[8 * 256];
  __shared__ float wg[C * 8];
  __shared__ float wg9[8 * 9];
  const int t = threadIdx.x;
  const int bb = blockIdx.x / (NTX * NTY);
  const int tile = blockIdx.x % (NTX * NTY);
  const int ty = tile / NTX, tx = tile % NTX;
  const int hyy = t / HSX, hxx = t % HSX;
  const int hy = ty * TSY - 1 + hyy;
  const int hx = tx * TSX - 1 + hxx;
  const bool hin = (t < NHALO) && (hy >= 0) && (hy < H) && (hx >= 0) && (hx < W);
  const float* xb = x + (size_t)bb * C * HW + (hin ? (hy * W + hx) : 0);
#pragma unroll
  for (int ic = 0; ic < C; ++ic)
    xs[ic * 256 + t] = hin ? xb[(size_t)ic * HW] : 0.f;
  const int py = t / TSX, px = t % TSX;
  const int gy = ty * TSY + py, gx = tx * TSX + px;
  const bool pin = (t < NPIX2) && (gy < H);
  const int hpos = py * HSX + px;
  for (int grp = 0; grp < 18; ++grp) {
    const int ch0 = grp * 8;
    {
      const int j = t + ((t < 128) ? 256 : 0);
      if (t < 128) {
        const int ic = t >> 3, g = t & 7;
        wg[t] = w1[(ch0 + g) * C + ic];
        const int ic2 = j >> 3, g2 = j & 7;
        wg[j] = w1[(ch0 + g2) * C + ic2];
      } else if (t < 256) {
        const int r = t - 128;
        const int ic = (r + 128) >> 3, g = (r + 128) & 7;
        wg[r + 128] = w1[(ch0 + g) * C + ic];
      }
      if (t < 72) wg9[t] = w9[ch0 * 9 + t];
    }
    __syncthreads();
    float a[8];
#pragma unroll
    for (int g = 0; g < 8; ++g) a[g] = 0.f;
#pragma unroll 4
    for (int ic = 0; ic < C; ++ic) {
      const float xsv = xs[ic * 256 + t];
      const float4 w0 = *(const float4*)&wg[ic * 8];
      const float4 w4 = *(const float4*)&wg[ic * 8 + 4];
      a[0] = fmaf(w0.x, xsv, a[0]);
      a[1] = fmaf(w0.y, xsv, a[1]);
      a[2] = fmaf(w0.z, xsv, a[2]);
      a[3] = fmaf(w0.w, xsv, a[3]);
      a[4] = fmaf(w4.x, xsv, a[4]);
      a[5] = fmaf(w4.y, xsv, a[5]);
      a[6] = fmaf(w4.z, xsv, a[6]);
      a[7] = fmaf(w4.w, xsv, a[7]);
    }
#pragma unroll
    for (int g = 0; g < 8; ++g) qs[g * 256 + t] = a[g];
    __syncthreads();
    if (t < NPIX2) {
#pragma unroll
      for (int g = 0; g < 8; ++g) {
        const int ch = ch0 + g;
        const float* w9p = wg9 + g * 9;
        const float* q = qs + g * 256 + hpos;
        float d = w9p[0] * q[0] + w9p[1] * q[1] + w9p[2] * q[2];
        d = fmaf(w9p[3], q[HSX], d);
        d = fmaf(w9p[4], q[HSX + 1], d);
        d = fmaf(w9p[5], q[HSX + 2], d);
        d = fmaf(w9p[6], q[2 * HSX], d);
        d = fmaf(w9p[7], q[2 * HSX + 1], d);
        d = fmaf(w9p[8], q[2 * HSX + 2], d);
        if (pin) {
          float* dst;
          int cc;
          if (ch < C)          { dst = dwq; cc = ch; }
          else if (ch < 2 * C) { dst = dwk; cc = ch - C; }
          else                 { dst = vout; cc = ch - 2 * C; }
          dst[((size_t)bb * C + cc) * HW + gy * W + gx] = d;
        }
      }
    }
    __syncthreads();
  }
}

// A2: per-chunk Gram partials + norm partials. Round-9: pixel-vectorized --
// 6 ds_read_b128 per 36 FMA (was 6 b32 per 9 FMA, LDS-pipe-bound at ~25%
// VALU). Summation order unchanged (pp ascending) -> bitwise-identical.
__global__ __launch_bounds__(256) void a2_gram(
    const float* __restrict__ dwq, const float* __restrict__ dwk,
    float* __restrict__ Sp, float* __restrict__ nqp, float* __restrict__ nkp) {
  __shared__ float qs[C * LP];
  __shared__ float ks[C * LP];
  const int tid = threadIdx.x;
  const int bb = blockIdx.x / NCHUNK;
  const int chunk = blockIdx.x % NCHUNK;
  const int base = chunk * CHUNK;
  const float* qb = dwq + (size_t)bb * C * HW + base;
  const float* kb = dwk + (size_t)bb * C * HW + base;
  const int c0 = (tid >> 4) * 3;
  const int d0 = (tid & 15) * 3;
  float acc[3][3] = {{0.f}};
  float nacc = 0.f;
  for (int sub = 0; sub < CHUNK / 64; ++sub) {
    __syncthreads();
#pragma unroll
    for (int j = 0; j < 3; ++j) {                 // 768 float4 = 48x64
      const int f = tid + j * 256;
      const int cc = f >> 4, p4 = (f & 15) * 4;
      *(float4*)&qs[cc * LP + p4] = *(const float4*)&qb[(size_t)cc * HW + sub * 64 + p4];
      *(float4*)&ks[cc * LP + p4] = *(const float4*)&kb[(size_t)cc * HW + sub * 64 + p4];
    }
    __syncthreads();
    if (tid < C) {
#pragma unroll
      for (int pq = 0; pq < 64; pq += 4) {
        const float4 v = *(const float4*)&qs[tid * LP + pq];
        nacc = fmaf(v.x, v.x, nacc);
        nacc = fmaf(v.y, v.y, nacc);
        nacc = fmaf(v.z, v.z, nacc);
        nacc = fmaf(v.w, v.w, nacc);
      }
    } else if (tid >= 64 && tid < 64 + C) {
      const int cq = tid - 64;
#pragma unroll
      for (int pq = 0; pq < 64; pq += 4) {
        const float4 v = *(const float4*)&ks[cq * LP + pq];
        nacc = fmaf(v.x, v.x, nacc);
        nacc = fmaf(v.y, v.y, nacc);
        nacc = fmaf(v.z, v.z, nacc);
        nacc = fmaf(v.w, v.w, nacc);
      }
    }
#pragma unroll 4
    for (int pq = 0; pq < 64; pq += 4) {
      const float4 q0 = *(const float4*)&qs[(c0 + 0) * LP + pq];
      const float4 q1 = *(const float4*)&qs[(c0 + 1) * LP + pq];
      const float4 q2 = *(const float4*)&qs[(c0 + 2) * LP + pq];
      const float4 k0 = *(const float4*)&ks[(d0 + 0) * LP + pq];
      const float4 k1 = *(const float4*)&ks[(d0 + 1) * LP + pq];
      const float4 k2 = *(const float4*)&ks[(d0 + 2) * LP + pq];
      const float qa[3][4] = {{q0.x, q0.y, q0.z, q0.w},
                              {q1.x, q1.y, q1.z, q1.w},
                              {q2.x, q2.y, q2.z, q2.w}};
      const float ka[3][4] = {{k0.x, k0.y, k0.z, k0.w},
                              {k1.x, k1.y, k1.z, k1.w},
                              {k2.x, k2.y, k2.z, k2.w}};
#pragma unroll
      for (int p = 0; p < 4; ++p)
#pragma unroll
        for (int i = 0; i < 3; ++i)
#pragma unroll
          for (int j = 0; j < 3; ++j)
            acc[i][j] = fmaf(qa[i][p], ka[j][p], acc[i][j]);
    }
  }
  float* Sb = Sp + ((size_t)bb * NCHUNK + chunk) * C * C;
#pragma unroll
  for (int i = 0; i < 3; ++i)
#pragma unroll
    for (int j = 0; j < 3; ++j)
      Sb[(c0 + i) * C + (d0 + j)] = acc[i][j];
  if (tid < C)                        nqp[((size_t)bb * NCHUNK + chunk) * C + tid] = nacc;
  else if (tid >= 64 && tid < 64 + C) nkp[((size_t)bb * NCHUNK + chunk) * C + (tid - 64)] = nacc;
}

// A3a: flat parallel reduction of the chunk partials.
#define RED_N (B * C * C + 2 * B * C)   // 9600
__global__ __launch_bounds__(256) void a3a_reduce(
    const float* __restrict__ Sp, const float* __restrict__ nqp,
    const float* __restrict__ nkp, float* __restrict__ S,
    float* __restrict__ nq, float* __restrict__ nk) {
  const int gid = blockIdx.x * 256 + threadIdx.x;
  if (gid < B * C * C) {
    const int bb = gid / (C * C), j = gid - bb * (C * C);
    const float* src = Sp + (size_t)bb * NCHUNK * C * C + j;
    float s = 0.f;
#pragma unroll 8
    for (int i = 0; i < NCHUNK; ++i) s += src[(size_t)i * C * C];
    S[gid] = s;
  } else if (gid < B * C * C + B * C) {
    const int r = gid - B * C * C;
    const int bb = r / C, j = r - bb * C;
    const float* src = nqp + (size_t)bb * NCHUNK * C + j;
    float s = 0.f;
#pragma unroll 8
    for (int i = 0; i < NCHUNK; ++i) s += src[(size_t)i * C];
    nq[r] = s;
  } else if (gid < RED_N) {
    const int r = gid - B * C * C - B * C;
    const int bb = r / C, j = r - bb * C;
    const float* src = nkp + (size_t)bb * NCHUNK * C + j;
    float s = 0.f;
#pragma unroll 8
    for (int i = 0; i < NCHUNK; ++i) s += src[(size_t)i * C];
    nk[r] = s;
  }
}

// A3b: normalize S, softmax rows, fold proj. Round-9: writes the TRANSPOSED
// fold MT[d][e] = (proj_w @ attn)[e][d] so a4 can read contiguous e-rows.
__global__ __launch_bounds__(64) void a3b_attn(
    const float* __restrict__ S, const float* __restrict__ nq,
    const float* __restrict__ nk, const float* __restrict__ proj_w,
    const float* __restrict__ temperature, float* __restrict__ MT) {
  __shared__ float A[C * C];
  __shared__ float knl[C];
  const int bb = blockIdx.x;
  const int t = threadIdx.x;
  const float T = temperature[0];
  if (t < C) knl[t] = fmaxf(sqrtf(nk[bb * C + t]), EPSN);
  __syncthreads();
  if (t < C) {
    const float qn = fmaxf(sqrtf(nq[bb * C + t]), EPSN);
    float row[C];
    float m = -1e30f;
    for (int d = 0; d < C; ++d) {
      const float v = S[(size_t)bb * C * C + t * C + d] / (qn * knl[d]) * T;
      row[d] = v;
      m = fmaxf(m, v);
    }
    float sum = 0.f;
    for (int d = 0; d < C; ++d) { const float e = expf(row[d] - m); row[d] = e; sum += e; }
    const float inv = 1.f / sum;
    for (int d = 0; d < C; ++d) A[t * C + d] = row[d] * inv;
  }
  __syncthreads();
  for (int idx = t; idx < C * C; idx += 64) {
    const int e = idx / C, d = idx % C;
    float acc = 0.f;
    for (int cc = 0; cc < C; ++cc) acc = fmaf(proj_w[e * C + cc], A[cc * C + d], acc);
    MT[(size_t)bb * C * C + d * C + e] = acc;
  }
}

// A4: out[e,p] = sum_d MT[d,e]*v[d,p], in place on d_out. Round-9: same
// structure as s_conv1x1 -- 256-px tile (48 KB), 4 px/thread (b128 LDS),
// wave owns 12 e, MT rows via per-lane VMEM (L1-resident 9 KB).
__global__ __launch_bounds__(256) void a4_apply(
    float* __restrict__ out, const float* __restrict__ MT) {
  __shared__ float vs[C * 256];  // 48 KB
  const int t = threadIdx.x;
  const int bb = blockIdx.x >> 8;                // 256 tiles per batch
  const int p0 = (blockIdx.x & 255) << 8;        // 256 px per tile
  float* ob = out + (size_t)bb * C * HW + p0;
#pragma unroll
  for (int j = 0; j < 12; ++j) {                 // 3072 float4 = 48x256
    const int f = t + j * 256;
    const int d = f >> 6, p4 = (f & 63) * 4;
    *(float4*)&vs[d * 256 + p4] = *(const float4*)&ob[(size_t)d * HW + p4];
  }
  __syncthreads();
  const int pl = (t & 63) * 4;
  const int e0 = force_vgpr((t >> 6) * 12);      // divergent -> VMEM M loads
  const float* mb = MT + (size_t)bb * C * C + e0;
  float acc[12][4];
#pragma unroll
  for (int o = 0; o < 12; ++o)
#pragma unroll
    for (int p = 0; p < 4; ++p) acc[o][p] = 0.f;
#pragma unroll 4
  for (int d = 0; d < C; ++d) {
    const float4 xv = *(const float4*)&vs[d * 256 + pl];
    const float xa[4] = {xv.x, xv.y, xv.z, xv.w};
#pragma unroll
    for (int jj = 0; jj < 3; ++jj) {
      const float4 wv = *(const float4*)&mb[d * C + jj * 4];
      const float wa[4] = {wv.x, wv.y, wv.z, wv.w};
#pragma unroll
      for (int o = 0; o < 4; ++o)
#pragma unroll
        for (int p = 0; p < 4; ++p)
          acc[jj * 4 + o][p] = fmaf(wa[o], xa[p], acc[jj * 4 + o][p]);
    }
  }
#pragma unroll
  for (int o = 0; o < 12; ++o) {
    float4 v;
    v.x = acc[o][0]; v.y = acc[o][1]; v.z = acc[o][2]; v.w = acc[o][3];
    *(float4*)&ob[(size_t)(e0 + o) * HW + pl] = v;
  }
}

// ==================== PATH B (fallback) kernels ==============================

__global__ __launch_bounds__(256) void k0_zero(float* __restrict__ ws) {
  const int i = blockIdx.x * 256 + threadIdx.x;
  if (i < B_ZERO_N) ws[i] = 0.f;
}

#define TS 14
#define HS 16
#define NT 19
#define NPIX 196

__global__ __launch_bounds__(256) void k1_fused(
    const float* __restrict__ x, const float* __restrict__ w1,
    const float* __restrict__ w9, float* __restrict__ vout,
    float* __restrict__ S, float* __restrict__ nq, float* __restrict__ nk) {
  __shared__ float qs[4 * 256];
  __shared__ float qt[NPIX * C];
  __shared__ float kt[NPIX * C];
  const int t = threadIdx.x;
  const int bb = blockIdx.x / (NT * NT);
  const int tile = blockIdx.x % (NT * NT);
  const int ty = tile / NT, tx = tile % NT;
  const int hy = ty * TS - 1 + (t >> 4);
  const int hx = tx * TS - 1 + (t & 15);
  const bool hin = (hy >= 0 && hy < H && hx >= 0 && hx < W);
  const float* xb = x + (size_t)bb * C * HW;
  float xv[C];
#pragma unroll
  for (int ic = 0; ic < C; ++ic)
    xv[ic] = hin ? xb[(size_t)ic * HW + hy * W + hx] : 0.f;
  const int py = t / TS, px = t % TS;
  const int gy = ty * TS + py, gx = tx * TS + px;
  const bool pin = (t < NPIX) && (gy < H) && (gx < W);
  for (int grp = 0; grp < 36; ++grp) {
    const int ch0 = grp * 4;
    const float* wp = w1 + ch0 * C;
    float a0 = 0.f, a1 = 0.f, a2 = 0.f, a3 = 0.f;
#pragma unroll
    for (int ic = 0; ic < C; ++ic) {
      const float xs = xv[ic];
      a0 = fmaf(wp[ic], xs, a0);
      a1 = fmaf(wp[C + ic], xs, a1);
      a2 = fmaf(wp[2 * C + ic], xs, a2);
      a3 = fmaf(wp[3 * C + ic], xs, a3);
    }
    qs[0 * 256 + t] = a0;
    qs[1 * 256 + t] = a1;
    qs[2 * 256 + t] = a2;
    qs[3 * 256 + t] = a3;
    __syncthreads();
    if (t < NPIX) {
#pragma unroll
      for (int g = 0; g < 4; ++g) {
        const int ch = ch0 + g;
        const float* w9p = w9 + ch * 9;
        const float* q = qs + g * 256 + py * HS + px;
        float d = w9p[0] * q[0] + w9p[1] * q[1] + w9p[2] * q[2];
        d = fmaf(w9p[3], q[HS], d);
        d = fmaf(w9p[4], q[HS + 1], d);
        d = fmaf(w9p[5], q[HS + 2], d);
        d = fmaf(w9p[6], q[2 * HS], d);
        d = fmaf(w9p[7], q[2 * HS + 1], d);
        d = fmaf(w9p[8], q[2 * HS + 2], d);
        if (ch < C)          qt[t * C + ch] = pin ? d : 0.f;
        else if (ch < 2 * C) kt[t * C + (ch - C)] = pin ? d : 0.f;
        else if (pin)        vout[((size_t)bb * C + (ch - 2 * C)) * HW + gy * W + gx] = d;
      }
    }
    __syncthreads();
  }
  if (t < C) {
    float s = 0.f;
    for (int p = 0; p < NPIX; ++p) { const float v = qt[p * C + t]; s = fmaf(v, v, s); }
    atomicAdd(&nq[bb * C + t], s);
  } else if (t >= 64 && t < 64 + C) {
    const int c = t - 64;
    float s = 0.f;
    for (int p = 0; p < NPIX; ++p) { const float v = kt[p * C + c]; s = fmaf(v, v, s); }
    atomicAdd(&nk[bb * C + c], s);
  }
  {
    const int part = t >> 6;
    const int idx = t & 63;
    const int c0 = (idx >> 3) * 6;
    const int d0 = (idx & 7) * 6;
    float acc[6][6] = {{0.f}};
    const int p0 = part * 49;
    for (int p = p0; p < p0 + 49; ++p) {
      float qv[6], kv[6];
#pragma unroll
      for (int j = 0; j < 6; ++j) { qv[j] = qt[p * C + c0 + j]; kv[j] = kt[p * C + d0 + j]; }
#pragma unroll
      for (int i = 0; i < 6; ++i)
#pragma unroll
        for (int j = 0; j < 6; ++j) acc[i][j] = fmaf(qv[i], kv[j], acc[i][j]);
    }
    float* Sb = S + (size_t)bb * C * C;
#pragma unroll
    for (int i = 0; i < 6; ++i)
#pragma unroll
      for (int j = 0; j < 6; ++j) atomicAdd(&Sb[(c0 + i) * C + (d0 + j)], acc[i][j]);
  }
}

// =============================================================================

extern "C" void kernel_launch(void* const* d_in, const int* in_sizes, int n_in,
                              void* d_out, int out_size, void* d_ws, size_t ws_size,
                              hipStream_t stream) {
  const float* x      = (const float*)d_in[0];
  const float* qkv_w  = (const float*)d_in[1];
  const float* dw_w   = (const float*)d_in[2];
  const float* proj_w = (const float*)d_in[3];
  const float* temp   = (const float*)d_in[4];
  float* out = (float*)d_out;
  float* ws  = (float*)d_ws;

  if (ws_size >= S_FLOATS * sizeof(float)) {
    float* qkv = ws + S_QKV_OFF;
    float* dwq = ws + S_DWQ_OFF;
    float* dwk = ws + S_DWK_OFF;
    float* Sp  = ws + S_SP_OFF;
    float* nqp = ws + S_NQP_OFF;
    float* nkp = ws + S_NKP_OFF;
    float* S   = ws + S_S_OFF;
    float* nq  = ws + S_NQ_OFF;
    float* nk  = ws + S_NK_OFF;
    float* MT  = ws + S_M_OFF;
    float* wT  = ws + S_WT_OFF;
    s_wt<<<(C3 * C + 255) / 256, 256, 0, stream>>>(qkv_w, wT);
    s_conv1x1<<<B * 256, 256, 0, stream>>>(x, wT, qkv);
    s_dw<<<B * C3 * 16, 256, 0, stream>>>(qkv, dw_w, dwq, dwk, out);
    a2_gram<<<B * NCHUNK, 256, 0, stream>>>(dwq, dwk, Sp, nqp, nkp);
    a3a_reduce<<<(RED_N + 255) / 256, 256, 0, stream>>>(Sp, nqp, nkp, S, nq, nk);
    a3b_attn<<<B, 64, 0, stream>>>(S, nq, nk, proj_w, temp, MT);
    a4_apply<<<B * 256, 256, 0, stream>>>(out, MT);
  } else if (ws_size >= A_FLOATS * sizeof(float)) {
    float* dwq = ws + A_DWQ_OFF;
    float* dwk = ws + A_DWK_OFF;
    float* Sp  = ws + A_SP_OFF;
    float* nqp = ws + A_NQP_OFF;
    float* nkp = ws + A_NKP_OFF;
    float* S   = ws + A_S_OFF;
    float* nq  = ws + A_NQ_OFF;
    float* nk  = ws + A_NK_OFF;
    float* MT  = ws + A_M_OFF;
    a1_conv_dw<<<B * NTX * NTY, 256, 0, stream>>>(x, qkv_w, dw_w, dwq, dwk, out);
    a2_gram<<<B * NCHUNK, 256, 0, stream>>>(dwq, dwk, Sp, nqp, nkp);
    a3a_reduce<<<(RED_N + 255) / 256, 256, 0, stream>>>(Sp, nqp, nkp, S, nq, nk);
    a3b_attn<<<B, 64, 0, stream>>>(S, nq, nk, proj_w, temp, MT);
    a4_apply<<<B * 256, 256, 0, stream>>>(out, MT);
  } else {
    float* S  = ws + B_S_OFF;
    float* nq = ws + B_NQ_OFF;
    float* nk = ws + B_NK_OFF;
    float* MT = ws + B_M_OFF;
    k0_zero<<<(B_ZERO_N + 255) / 256, 256, 0, stream>>>(ws);
    k1_fused<<<B * NT * NT, 256, 0, stream>>>(x, qkv_w, dw_w, out, S, nq, nk);
    a3b_attn<<<B, 64, 0, stream>>>(S, nq, nk, proj_w, temp, MT);
    a4_apply<<<B * 256, 256, 0, stream>>>(out, MT);
  }
}

// Round 4
// 337.818 us; speedup vs baseline: 1.0260x; 1.0260x over previous
//
#include <hip/hip_runtime.h>

#define B 4
#define C 48
#define C3 144
#define H 256
#define W 256
#define HW 65536
#define EPSN 1e-12f

// ---- a1 tiling: 16x12 output tile, 18x14 halo (252 positions) ----
#define TSX 16
#define TSY 12
#define HSX 18
#define HSY 14
#define NTX 16           // 256/16
#define NTY 22           // ceil(256/12)
#define NPIX2 192        // TSX*TSY
#define NHALO 252        // HSX*HSY

#define NCHUNK 128       // gram chunks per batch
#define CHUNK 512        // pixels per gram chunk
#define LP 68            // padded LDS row stride for a2 (float4-aligned, <=2-way banks)

// Round-10 theory: all dispatches plateau at ~2.1 TB/s with 20-26% occupancy
// -> memory-LATENCY bound (too few blocks/CU in flight), not pipe-bound
// (VALUBusy*dur == FMA floor in every weight-path variant). Fixes:
// s_conv1x1/a4 tiles halved to 128 px (24 KB LDS -> 6 blocks/CU, 24 waves);
// weights on the s_load path (SMEM latency now hidden by 6 waves/SIMD);
// a2 (grid-capped 2 blocks/CU) gets register double-buffered staging (T14)
// so sub+1's HBM loads fly under sub's gram FMAs. All summation orders
// unchanged -> bitwise-identical output.
#define S_QKV_OFF  ((size_t)0)
#define S_DWQ_OFF  (S_QKV_OFF + (size_t)B * C3 * HW)
#define S_DWK_OFF  (S_DWQ_OFF + (size_t)B * C * HW)
#define S_SP_OFF   (S_DWK_OFF + (size_t)B * C * HW)
#define S_NQP_OFF  (S_SP_OFF + (size_t)B * NCHUNK * C * C)
#define S_NKP_OFF  (S_NQP_OFF + (size_t)B * NCHUNK * C)
#define S_S_OFF    (S_NKP_OFF + (size_t)B * NCHUNK * C)
#define S_NQ_OFF   (S_S_OFF + (size_t)B * C * C)
#define S_NK_OFF   (S_NQ_OFF + (size_t)B * C)
#define S_M_OFF    (S_NK_OFF + (size_t)B * C)
#define S_WT_OFF   (S_M_OFF + (size_t)B * C * C)
#define S_FLOATS   (S_WT_OFF + (size_t)C3 * C)

// ================= PATH A workspace layout (floats), ~106 MB =================
#define A_DWQ_OFF  ((size_t)0)
#define A_DWK_OFF  (A_DWQ_OFF + (size_t)B * C * HW)
#define A_SP_OFF   (A_DWK_OFF + (size_t)B * C * HW)            // B*128*2304
#define A_NQP_OFF  (A_SP_OFF + (size_t)B * NCHUNK * C * C)     // B*128*48
#define A_NKP_OFF  (A_NQP_OFF + (size_t)B * NCHUNK * C)
#define A_S_OFF    (A_NKP_OFF + (size_t)B * NCHUNK * C)        // B*2304
#define A_NQ_OFF   (A_S_OFF + (size_t)B * C * C)               // B*48
#define A_NK_OFF   (A_NQ_OFF + (size_t)B * C)
#define A_M_OFF    (A_NK_OFF + (size_t)B * C)                  // B*2304
#define A_FLOATS   (A_M_OFF + (size_t)B * C * C)

// ================= PATH B (fallback) workspace layout, ~75 KB ================
#define B_S_OFF  0
#define B_NQ_OFF (B * C * C)
#define B_NK_OFF (B_NQ_OFF + B * C)
#define B_M_OFF  (B_NK_OFF + B * C)
#define B_ZERO_N (B * C * C + 2 * B * C)

// ============================ PATH S kernels =================================

// S0: transpose qkv 1x1 weights [144][48] -> wT [48][144].
__global__ __launch_bounds__(256) void s_wt(
    const float* __restrict__ w1, float* __restrict__ wT) {
  const int i = blockIdx.x * 256 + threadIdx.x;
  if (i < C3 * C) {
    const int oc = i / C, d = i - oc * C;
    wT[d * C3 + oc] = w1[i];
  }
}

// S1: 1x1 conv as GEMM. Round-10: 128-px tile (24 KB LDS -> 6 blocks/CU),
// thread owns 2 px (ds_read_b64), wave owns 12 oc x 3 groups. Weights via
// wave-uniform s_load (round-2 path; latency now hidden by 24 waves/CU).
__global__ __launch_bounds__(256) void s_conv1x1(
    const float* __restrict__ x, const float* __restrict__ wT,
    float* __restrict__ qkv) {
  __shared__ float xs[C * 128];      // 24 KB
  const int t = threadIdx.x;
  const int bb = blockIdx.x >> 9;                // 512 pixel-tiles per batch
  const int p0 = (blockIdx.x & 511) << 7;        // 128 px per tile
  const float* xb = x + (size_t)bb * C * HW + p0;
#pragma unroll
  for (int j = 0; j < 6; ++j) {                  // 1536 float4 = 48x128
    const int f = t + j * 256;
    const int d = f >> 5, p4 = (f & 31) * 4;
    *(float4*)&xs[d * 128 + p4] = *(const float4*)&xb[(size_t)d * HW + p4];
  }
  __syncthreads();
  const int pl = (t & 63) * 2;                   // this thread's 2 pixels
  const int ocw = __builtin_amdgcn_readfirstlane((t >> 6) * 12);
#pragma unroll 1
  for (int g = 0; g < 3; ++g) {
    const int oc0 = g * 48 + ocw;                // provably wave-uniform
    const float* wp = wT + oc0;                  // uniform -> s_load base
    float acc[12][2];
#pragma unroll
    for (int o = 0; o < 12; ++o)
#pragma unroll
      for (int p = 0; p < 2; ++p) acc[o][p] = 0.f;
#pragma unroll 4
    for (int d = 0; d < C; ++d) {
      const float2 xv = *(const float2*)&xs[d * 128 + pl];
      const float xa[2] = {xv.x, xv.y};
#pragma unroll
      for (int jj = 0; jj < 3; ++jj) {
        const float4 wv = *(const float4*)&wp[d * C3 + jj * 4];
        const float wa[4] = {wv.x, wv.y, wv.z, wv.w};
#pragma unroll
        for (int o = 0; o < 4; ++o)
#pragma unroll
          for (int p = 0; p < 2; ++p)
            acc[jj * 4 + o][p] = fmaf(wa[o], xa[p], acc[jj * 4 + o][p]);
      }
    }
    float* ob = qkv + ((size_t)bb * C3 + oc0) * HW + p0 + pl;
#pragma unroll
    for (int o = 0; o < 12; ++o) {
      float2 v;
      v.x = acc[o][0]; v.y = acc[o][1];
      *(float2*)&ob[(size_t)o * HW] = v;
    }
  }
}

// S2: depthwise 3x3, streaming. Block = one (batch, channel, 16-row band).
// 18.7 KB LDS -> 8 blocks/CU (full occupancy). 4 px/thread, b128+b64 reads.
#define DWR 16
__global__ __launch_bounds__(256) void s_dw(
    const float* __restrict__ qkv, const float* __restrict__ w9,
    float* __restrict__ dwq, float* __restrict__ dwk,
    float* __restrict__ vout) {
  __shared__ float ls[18 * 260];
  const int t = threadIdx.x;
  const int rblk = blockIdx.x & 15;
  const int cb = blockIdx.x >> 4;                // bb*144 + c
  const int c = cb % C3;
  const int bb = cb / C3;
  const int r0 = rblk * DWR;
  const float* src = qkv + (size_t)cb * HW;
#pragma unroll
  for (int f = t; f < 18 * 256; f += 256) {      // 18 iterations exactly
    const int rr = f >> 8, xc = f & 255;
    const int gr = r0 - 1 + rr;
    ls[rr * 260 + 1 + xc] = (gr >= 0 && gr < H) ? src[gr * W + xc] : 0.f;
  }
  if (t < 18) { ls[t * 260] = 0.f; ls[t * 260 + 257] = 0.f; }
  const float* wp = w9 + c * 9;                  // uniform -> s_load (tiny)
  float wv[9];
#pragma unroll
  for (int k = 0; k < 9; ++k) wv[k] = wp[k];
  __syncthreads();
  float* dst;
  int cc;
  if (c < C)          { dst = dwq;  cc = c; }
  else if (c < 2 * C) { dst = dwk;  cc = c - C; }
  else                { dst = vout; cc = c - 2 * C; }
  float* ob = dst + ((size_t)bb * C + cc) * HW;
  const int xq = (t & 63) * 4;                   // 4 output cols per thread
  const int rw = t >> 6;                         // wave owns every 4th row
#pragma unroll
  for (int rr = rw; rr < DWR; rr += 4) {
    const float* l0 = ls + rr * 260 + xq;        // padded col xq == global x-1
    const float4 a0 = *(const float4*)&l0[0];
    const float2 b0 = *(const float2*)&l0[4];
    const float4 a1 = *(const float4*)&l0[260];
    const float2 b1 = *(const float2*)&l0[264];
    const float4 a2 = *(const float4*)&l0[520];
    const float2 b2 = *(const float2*)&l0[524];
    const float r0e[6] = {a0.x, a0.y, a0.z, a0.w, b0.x, b0.y};
    const float r1e[6] = {a1.x, a1.y, a1.z, a1.w, b1.x, b1.y};
    const float r2e[6] = {a2.x, a2.y, a2.z, a2.w, b2.x, b2.y};
    float4 o;
    float* op = &o.x;
#pragma unroll
    for (int j = 0; j < 4; ++j) {
      float d = wv[0] * r0e[j] + wv[1] * r0e[j + 1] + wv[2] * r0e[j + 2];
      d = fmaf(wv[3], r1e[j], d);
      d = fmaf(wv[4], r1e[j + 1], d);
      d = fmaf(wv[5], r1e[j + 2], d);
      d = fmaf(wv[6], r2e[j], d);
      d = fmaf(wv[7], r2e[j + 1], d);
      d = fmaf(wv[8], r2e[j + 2], d);
      op[j] = d;
    }
    *(float4*)&ob[(r0 + rr) * W + xq] = o;
  }
}

// ============================ PATH A kernels =================================

// A1: 1x1 conv + depthwise 3x3 fused (fallback path only).
__global__ __launch_bounds__(256) void a1_conv_dw(
    const float* __restrict__ x, const float* __restrict__ w1,
    const float* __restrict__ w9, float* __restrict__ dwq,
    float* __restrict__ dwk, float* __restrict__ vout) {
  __shared__ float xs[C * 256];
  __shared__ float qs[8 * 256];
  __shared__ float wg[C * 8];
  __shared__ float wg9[8 * 9];
  const int t = threadIdx.x;
  const int bb = blockIdx.x / (NTX * NTY);
  const int tile = blockIdx.x % (NTX * NTY);
  const int ty = tile / NTX, tx = tile % NTX;
  const int hyy = t / HSX, hxx = t % HSX;
  const int hy = ty * TSY - 1 + hyy;
  const int hx = tx * TSX - 1 + hxx;
  const bool hin = (t < NHALO) && (hy >= 0) && (hy < H) && (hx >= 0) && (hx < W);
  const float* xb = x + (size_t)bb * C * HW + (hin ? (hy * W + hx) : 0);
#pragma unroll
  for (int ic = 0; ic < C; ++ic)
    xs[ic * 256 + t] = hin ? xb[(size_t)ic * HW] : 0.f;
  const int py = t / TSX, px = t % TSX;
  const int gy = ty * TSY + py, gx = tx * TSX + px;
  const bool pin = (t < NPIX2) && (gy < H);
  const int hpos = py * HSX + px;
  for (int grp = 0; grp < 18; ++grp) {
    const int ch0 = grp * 8;
    {
      const int j = t + ((t < 128) ? 256 : 0);
      if (t < 128) {
        const int ic = t >> 3, g = t & 7;
        wg[t] = w1[(ch0 + g) * C + ic];
        const int ic2 = j >> 3, g2 = j & 7;
        wg[j] = w1[(ch0 + g2) * C + ic2];
      } else if (t < 256) {
        const int r = t - 128;
        const int ic = (r + 128) >> 3, g = (r + 128) & 7;
        wg[r + 128] = w1[(ch0 + g) * C + ic];
      }
      if (t < 72) wg9[t] = w9[ch0 * 9 + t];
    }
    __syncthreads();
    float a[8];
#pragma unroll
    for (int g = 0; g < 8; ++g) a[g] = 0.f;
#pragma unroll 4
    for (int ic = 0; ic < C; ++ic) {
      const float xsv = xs[ic * 256 + t];
      const float4 w0 = *(const float4*)&wg[ic * 8];
      const float4 w4 = *(const float4*)&wg[ic * 8 + 4];
      a[0] = fmaf(w0.x, xsv, a[0]);
      a[1] = fmaf(w0.y, xsv, a[1]);
      a[2] = fmaf(w0.z, xsv, a[2]);
      a[3] = fmaf(w0.w, xsv, a[3]);
      a[4] = fmaf(w4.x, xsv, a[4]);
      a[5] = fmaf(w4.y, xsv, a[5]);
      a[6] = fmaf(w4.z, xsv, a[6]);
      a[7] = fmaf(w4.w, xsv, a[7]);
    }
#pragma unroll
    for (int g = 0; g < 8; ++g) qs[g * 256 + t] = a[g];
    __syncthreads();
    if (t < NPIX2) {
#pragma unroll
      for (int g = 0; g < 8; ++g) {
        const int ch = ch0 + g;
        const float* w9p = wg9 + g * 9;
        const float* q = qs + g * 256 + hpos;
        float d = w9p[0] * q[0] + w9p[1] * q[1] + w9p[2] * q[2];
        d = fmaf(w9p[3], q[HSX], d);
        d = fmaf(w9p[4], q[HSX + 1], d);
        d = fmaf(w9p[5], q[HSX + 2], d);
        d = fmaf(w9p[6], q[2 * HSX], d);
        d = fmaf(w9p[7], q[2 * HSX + 1], d);
        d = fmaf(w9p[8], q[2 * HSX + 2], d);
        if (pin) {
          float* dst;
          int cc;
          if (ch < C)          { dst = dwq; cc = ch; }
          else if (ch < 2 * C) { dst = dwk; cc = ch - C; }
          else                 { dst = vout; cc = ch - 2 * C; }
          dst[((size_t)bb * C + cc) * HW + gy * W + gx] = d;
        }
      }
    }
    __syncthreads();
  }
}

// A2: per-chunk Gram partials + norm partials. Round-10: register
// double-buffered staging (T14) -- sub+1's global loads issue right after
// sub's ds_writes and fly under the gram FMAs. FMA order unchanged.
__global__ __launch_bounds__(256) void a2_gram(
    const float* __restrict__ dwq, const float* __restrict__ dwk,
    float* __restrict__ Sp, float* __restrict__ nqp, float* __restrict__ nkp) {
  __shared__ float qs[C * LP];
  __shared__ float ks[C * LP];
  const int tid = threadIdx.x;
  const int bb = blockIdx.x / NCHUNK;
  const int chunk = blockIdx.x % NCHUNK;
  const int base = chunk * CHUNK;
  const float* qb = dwq + (size_t)bb * C * HW + base;
  const float* kb = dwk + (size_t)bb * C * HW + base;
  const int c0 = (tid >> 4) * 3;
  const int d0 = (tid & 15) * 3;
  float acc[3][3] = {{0.f}};
  float nacc = 0.f;
  float4 rq[3], rk[3];
#pragma unroll
  for (int j = 0; j < 3; ++j) {                  // prefetch sub 0
    const int f = tid + j * 256;
    const int cc = f >> 4, p4 = (f & 15) * 4;
    rq[j] = *(const float4*)&qb[(size_t)cc * HW + p4];
    rk[j] = *(const float4*)&kb[(size_t)cc * HW + p4];
  }
  for (int sub = 0; sub < CHUNK / 64; ++sub) {
    __syncthreads();                             // LDS free (prev compute done)
#pragma unroll
    for (int j = 0; j < 3; ++j) {
      const int f = tid + j * 256;
      const int cc = f >> 4, p4 = (f & 15) * 4;
      *(float4*)&qs[cc * LP + p4] = rq[j];
      *(float4*)&ks[cc * LP + p4] = rk[j];
    }
    if (sub < CHUNK / 64 - 1) {                  // issue next sub's loads
#pragma unroll
      for (int j = 0; j < 3; ++j) {
        const int f = tid + j * 256;
        const int cc = f >> 4, p4 = (f & 15) * 4;
        rq[j] = *(const float4*)&qb[(size_t)cc * HW + (sub + 1) * 64 + p4];
        rk[j] = *(const float4*)&kb[(size_t)cc * HW + (sub + 1) * 64 + p4];
      }
    }
    __syncthreads();
    if (tid < C) {
#pragma unroll
      for (int pq = 0; pq < 64; pq += 4) {
        const float4 v = *(const float4*)&qs[tid * LP + pq];
        nacc = fmaf(v.x, v.x, nacc);
        nacc = fmaf(v.y, v.y, nacc);
        nacc = fmaf(v.z, v.z, nacc);
        nacc = fmaf(v.w, v.w, nacc);
      }
    } else if (tid >= 64 && tid < 64 + C) {
      const int cq = tid - 64;
#pragma unroll
      for (int pq = 0; pq < 64; pq += 4) {
        const float4 v = *(const float4*)&ks[cq * LP + pq];
        nacc = fmaf(v.x, v.x, nacc);
        nacc = fmaf(v.y, v.y, nacc);
        nacc = fmaf(v.z, v.z, nacc);
        nacc = fmaf(v.w, v.w, nacc);
      }
    }
#pragma unroll 4
    for (int pq = 0; pq < 64; pq += 4) {
      const float4 q0 = *(const float4*)&qs[(c0 + 0) * LP + pq];
      const float4 q1 = *(const float4*)&qs[(c0 + 1) * LP + pq];
      const float4 q2 = *(const float4*)&qs[(c0 + 2) * LP + pq];
      const float4 k0 = *(const float4*)&ks[(d0 + 0) * LP + pq];
      const float4 k1 = *(const float4*)&ks[(d0 + 1) * LP + pq];
      const float4 k2 = *(const float4*)&ks[(d0 + 2) * LP + pq];
      const float qa[3][4] = {{q0.x, q0.y, q0.z, q0.w},
                              {q1.x, q1.y, q1.z, q1.w},
                              {q2.x, q2.y, q2.z, q2.w}};
      const float ka[3][4] = {{k0.x, k0.y, k0.z, k0.w},
                              {k1.x, k1.y, k1.z, k1.w},
                              {k2.x, k2.y, k2.z, k2.w}};
#pragma unroll
      for (int p = 0; p < 4; ++p)
#pragma unroll
        for (int i = 0; i < 3; ++i)
#pragma unroll
          for (int j = 0; j < 3; ++j)
            acc[i][j] = fmaf(qa[i][p], ka[j][p], acc[i][j]);
    }
  }
  float* Sb = Sp + ((size_t)bb * NCHUNK + chunk) * C * C;
#pragma unroll
  for (int i = 0; i < 3; ++i)
#pragma unroll
    for (int j = 0; j < 3; ++j)
      Sb[(c0 + i) * C + (d0 + j)] = acc[i][j];
  if (tid < C)                        nqp[((size_t)bb * NCHUNK + chunk) * C + tid] = nacc;
  else if (tid >= 64 && tid < 64 + C) nkp[((size_t)bb * NCHUNK + chunk) * C + (tid - 64)] = nacc;
}

// A3a: flat parallel reduction of the chunk partials.
#define RED_N (B * C * C + 2 * B * C)   // 9600
__global__ __launch_bounds__(256) void a3a_reduce(
    const float* __restrict__ Sp, const float* __restrict__ nqp,
    const float* __restrict__ nkp, float* __restrict__ S,
    float* __restrict__ nq, float* __restrict__ nk) {
  const int gid = blockIdx.x * 256 + threadIdx.x;
  if (gid < B * C * C) {
    const int bb = gid / (C * C), j = gid - bb * (C * C);
    const float* src = Sp + (size_t)bb * NCHUNK * C * C + j;
    float s = 0.f;
#pragma unroll 8
    for (int i = 0; i < NCHUNK; ++i) s += src[(size_t)i * C * C];
    S[gid] = s;
  } else if (gid < B * C * C + B * C) {
    const int r = gid - B * C * C;
    const int bb = r / C, j = r - bb * C;
    const float* src = nqp + (size_t)bb * NCHUNK * C + j;
    float s = 0.f;
#pragma unroll 8
    for (int i = 0; i < NCHUNK; ++i) s += src[(size_t)i * C];
    nq[r] = s;
  } else if (gid < RED_N) {
    const int r = gid - B * C * C - B * C;
    const int bb = r / C, j = r - bb * C;
    const float* src = nkp + (size_t)bb * NCHUNK * C + j;
    float s = 0.f;
#pragma unroll 8
    for (int i = 0; i < NCHUNK; ++i) s += src[(size_t)i * C];
    nk[r] = s;
  }
}

// A3b: normalize S, softmax rows, fold proj; writes transposed MT[d][e].
__global__ __launch_bounds__(64) void a3b_attn(
    const float* __restrict__ S, const float* __restrict__ nq,
    const float* __restrict__ nk, const float* __restrict__ proj_w,
    const float* __restrict__ temperature, float* __restrict__ MT) {
  __shared__ float A[C * C];
  __shared__ float knl[C];
  const int bb = blockIdx.x;
  const int t = threadIdx.x;
  const float T = temperature[0];
  if (t < C) knl[t] = fmaxf(sqrtf(nk[bb * C + t]), EPSN);
  __syncthreads();
  if (t < C) {
    const float qn = fmaxf(sqrtf(nq[bb * C + t]), EPSN);
    float row[C];
    float m = -1e30f;
    for (int d = 0; d < C; ++d) {
      const float v = S[(size_t)bb * C * C + t * C + d] / (qn * knl[d]) * T;
      row[d] = v;
      m = fmaxf(m, v);
    }
    float sum = 0.f;
    for (int d = 0; d < C; ++d) { const float e = expf(row[d] - m); row[d] = e; sum += e; }
    const float inv = 1.f / sum;
    for (int d = 0; d < C; ++d) A[t * C + d] = row[d] * inv;
  }
  __syncthreads();
  for (int idx = t; idx < C * C; idx += 64) {
    const int e = idx / C, d = idx % C;
    float acc = 0.f;
    for (int cc = 0; cc < C; ++cc) acc = fmaf(proj_w[e * C + cc], A[cc * C + d], acc);
    MT[(size_t)bb * C * C + d * C + e] = acc;
  }
}

// A4: out[e,p] = sum_d MT[d,e]*v[d,p], in place on d_out. Round-10: 128-px
// tile (24 KB -> 6 blocks/CU), 2 px/thread, MT rows via wave-uniform s_load.
__global__ __launch_bounds__(256) void a4_apply(
    float* __restrict__ out, const float* __restrict__ MT) {
  __shared__ float vs[C * 128];  // 24 KB
  const int t = threadIdx.x;
  const int bb = blockIdx.x >> 9;                // 512 tiles per batch
  const int p0 = (blockIdx.x & 511) << 7;        // 128 px per tile
  float* ob = out + (size_t)bb * C * HW + p0;
#pragma unroll
  for (int j = 0; j < 6; ++j) {                  // 1536 float4 = 48x128
    const int f = t + j * 256;
    const int d = f >> 5, p4 = (f & 31) * 4;
    *(float4*)&vs[d * 128 + p4] = *(const float4*)&ob[(size_t)d * HW + p4];
  }
  __syncthreads();
  const int pl = (t & 63) * 2;
  const int e0 = __builtin_amdgcn_readfirstlane((t >> 6) * 12);
  const float* mb = MT + (size_t)bb * C * C + e0;  // uniform -> s_load
  float acc[12][2];
#pragma unroll
  for (int o = 0; o < 12; ++o)
#pragma unroll
    for (int p = 0; p < 2; ++p) acc[o][p] = 0.f;
#pragma unroll 4
  for (int d = 0; d < C; ++d) {
    const float2 xv = *(const float2*)&vs[d * 128 + pl];
    const float xa[2] = {xv.x, xv.y};
#pragma unroll
    for (int jj = 0; jj < 3; ++jj) {
      const float4 wv = *(const float4*)&mb[d * C + jj * 4];
      const float wa[4] = {wv.x, wv.y, wv.z, wv.w};
#pragma unroll
      for (int o = 0; o < 4; ++o)
#pragma unroll
        for (int p = 0; p < 2; ++p)
          acc[jj * 4 + o][p] = fmaf(wa[o], xa[p], acc[jj * 4 + o][p]);
    }
  }
#pragma unroll
  for (int o = 0; o < 12; ++o) {
    float2 v;
    v.x = acc[o][0]; v.y = acc[o][1];
    *(float2*)&ob[(size_t)(e0 + o) * HW + pl] = v;
  }
}

// ==================== PATH B (fallback) kernels ==============================

__global__ __launch_bounds__(256) void k0_zero(float* __restrict__ ws) {
  const int i = blockIdx.x * 256 + threadIdx.x;
  if (i < B_ZERO_N) ws[i] = 0.f;
}

#define TS 14
#define HS 16
#define NT 19
#define NPIX 196

__global__ __launch_bounds__(256) void k1_fused(
    const float* __restrict__ x, const float* __restrict__ w1,
    const float* __restrict__ w9, float* __restrict__ vout,
    float* __restrict__ S, float* __restrict__ nq, float* __restrict__ nk) {
  __shared__ float qs[4 * 256];
  __shared__ float qt[NPIX * C];
  __shared__ float kt[NPIX * C];
  const int t = threadIdx.x;
  const int bb = blockIdx.x / (NT * NT);
  const int tile = blockIdx.x % (NT * NT);
  const int ty = tile / NT, tx = tile % NT;
  const int hy = ty * TS - 1 + (t >> 4);
  const int hx = tx * TS - 1 + (t & 15);
  const bool hin = (hy >= 0 && hy < H && hx >= 0 && hx < W);
  const float* xb = x + (size_t)bb * C * HW;
  float xv[C];
#pragma unroll
  for (int ic = 0; ic < C; ++ic)
    xv[ic] = hin ? xb[(size_t)ic * HW + hy * W + hx] : 0.f;
  const int py = t / TS, px = t % TS;
  const int gy = ty * TS + py, gx = tx * TS + px;
  const bool pin = (t < NPIX) && (gy < H) && (gx < W);
  for (int grp = 0; grp < 36; ++grp) {
    const int ch0 = grp * 4;
    const float* wp = w1 + ch0 * C;
    float a0 = 0.f, a1 = 0.f, a2 = 0.f, a3 = 0.f;
#pragma unroll
    for (int ic = 0; ic < C; ++ic) {
      const float xs = xv[ic];
      a0 = fmaf(wp[ic], xs, a0);
      a1 = fmaf(wp[C + ic], xs, a1);
      a2 = fmaf(wp[2 * C + ic], xs, a2);
      a3 = fmaf(wp[3 * C + ic], xs, a3);
    }
    qs[0 * 256 + t] = a0;
    qs[1 * 256 + t] = a1;
    qs[2 * 256 + t] = a2;
    qs[3 * 256 + t] = a3;
    __syncthreads();
    if (t < NPIX) {
#pragma unroll
      for (int g = 0; g < 4; ++g) {
        const int ch = ch0 + g;
        const float* w9p = w9 + ch * 9;
        const float* q = qs + g * 256 + py * HS + px;
        float d = w9p[0] * q[0] + w9p[1] * q[1] + w9p[2] * q[2];
        d = fmaf(w9p[3], q[HS], d);
        d = fmaf(w9p[4], q[HS + 1], d);
        d = fmaf(w9p[5], q[HS + 2], d);
        d = fmaf(w9p[6], q[2 * HS], d);
        d = fmaf(w9p[7], q[2 * HS + 1], d);
        d = fmaf(w9p[8], q[2 * HS + 2], d);
        if (ch < C)          qt[t * C + ch] = pin ? d : 0.f;
        else if (ch < 2 * C) kt[t * C + (ch - C)] = pin ? d : 0.f;
        else if (pin)        vout[((size_t)bb * C + (ch - 2 * C)) * HW + gy * W + gx] = d;
      }
    }
    __syncthreads();
  }
  if (t < C) {
    float s = 0.f;
    for (int p = 0; p < NPIX; ++p) { const float v = qt[p * C + t]; s = fmaf(v, v, s); }
    atomicAdd(&nq[bb * C + t], s);
  } else if (t >= 64 && t < 64 + C) {
    const int c = t - 64;
    float s = 0.f;
    for (int p = 0; p < NPIX; ++p) { const float v = kt[p * C + c]; s = fmaf(v, v, s); }
    atomicAdd(&nk[bb * C + c], s);
  }
  {
    const int part = t >> 6;
    const int idx = t & 63;
    const int c0 = (idx >> 3) * 6;
    const int d0 = (idx & 7) * 6;
    float acc[6][6] = {{0.f}};
    const int p0 = part * 49;
    for (int p = p0; p < p0 + 49; ++p) {
      float qv[6], kv[6];
#pragma unroll
      for (int j = 0; j < 6; ++j) { qv[j] = qt[p * C + c0 + j]; kv[j] = kt[p * C + d0 + j]; }
#pragma unroll
      for (int i = 0; i < 6; ++i)
#pragma unroll
        for (int j = 0; j < 6; ++j) acc[i][j] = fmaf(qv[i], kv[j], acc[i][j]);
    }
    float* Sb = S + (size_t)bb * C * C;
#pragma unroll
    for (int i = 0; i < 6; ++i)
#pragma unroll
      for (int j = 0; j < 6; ++j) atomicAdd(&Sb[(c0 + i) * C + (d0 + j)], acc[i][j]);
  }
}

// =============================================================================

extern "C" void kernel_launch(void* const* d_in, const int* in_sizes, int n_in,
                              void* d_out, int out_size, void* d_ws, size_t ws_size,
                              hipStream_t stream) {
  const float* x      = (const float*)d_in[0];
  const float* qkv_w  = (const float*)d_in[1];
  const float* dw_w   = (const float*)d_in[2];
  const float* proj_w = (const float*)d_in[3];
  const float* temp   = (const float*)d_in[4];
  float* out = (float*)d_out;
  float* ws  = (float*)d_ws;

  if (ws_size >= S_FLOATS * sizeof(float)) {
    float* qkv = ws + S_QKV_OFF;
    float* dwq = ws + S_DWQ_OFF;
    float* dwk = ws + S_DWK_OFF;
    float* Sp  = ws + S_SP_OFF;
    float* nqp = ws + S_NQP_OFF;
    float* nkp = ws + S_NKP_OFF;
    float* S   = ws + S_S_OFF;
    float* nq  = ws + S_NQ_OFF;
    float* nk  = ws + S_NK_OFF;
    float* MT  = ws + S_M_OFF;
    float* wT  = ws + S_WT_OFF;
    s_wt<<<(C3 * C + 255) / 256, 256, 0, stream>>>(qkv_w, wT);
    s_conv1x1<<<B * 512, 256, 0, stream>>>(x, wT, qkv);
    s_dw<<<B * C3 * 16, 256, 0, stream>>>(qkv, dw_w, dwq, dwk, out);
    a2_gram<<<B * NCHUNK, 256, 0, stream>>>(dwq, dwk, Sp, nqp, nkp);
    a3a_reduce<<<(RED_N + 255) / 256, 256, 0, stream>>>(Sp, nqp, nkp, S, nq, nk);
    a3b_attn<<<B, 64, 0, stream>>>(S, nq, nk, proj_w, temp, MT);
    a4_apply<<<B * 512, 256, 0, stream>>>(out, MT);
  } else if (ws_size >= A_FLOATS * sizeof(float)) {
    float* dwq = ws + A_DWQ_OFF;
    float* dwk = ws + A_DWK_OFF;
    float* Sp  = ws + A_SP_OFF;
    float* nqp = ws + A_NQP_OFF;
    float* nkp = ws + A_NKP_OFF;
    float* S   = ws + A_S_OFF;
    float* nq  = ws + A_NQ_OFF;
    float* nk  = ws + A_NK_OFF;
    float* MT  = ws + A_M_OFF;
    a1_conv_dw<<<B * NTX * NTY, 256, 0, stream>>>(x, qkv_w, dw_w, dwq, dwk, out);
    a2_gram<<<B * NCHUNK, 256, 0, stream>>>(dwq, dwk, Sp, nqp, nkp);
    a3a_reduce<<<(RED_N + 255) / 256, 256, 0, stream>>>(Sp, nqp, nkp, S, nq, nk);
    a3b_attn<<<B, 64, 0, stream>>>(S, nq, nk, proj_w, temp, MT);
    a4_apply<<<B * 512, 256, 0, stream>>>(out, MT);
  } else {
    float* S  = ws + B_S_OFF;
    float* nq = ws + B_NQ_OFF;
    float* nk = ws + B_NK_OFF;
    float* MT = ws + B_M_OFF;
    k0_zero<<<(B_ZERO_N + 255) / 256, 256, 0, stream>>>(ws);
    k1_fused<<<B * NT * NT, 256, 0, stream>>>(x, qkv_w, dw_w, out, S, nq, nk);
    a3b_attn<<<B, 64, 0, stream>>>(S, nq, nk, proj_w, temp, MT);
    a4_apply<<<B * 512, 256, 0, stream>>>(out, MT);
  }
}